// Round 14
// baseline (989.784 us; speedup 1.0000x reference)
//
#include <hip/hip_runtime.h>
#include <hip/hip_bf16.h>
#include <cstdint>
#include <cstddef>

// H=8 D=256 R=6 S=2 K=2 EV=2, HID=2048, DV=512, b=2, t=1024
typedef __bf16 bf16_t;
typedef __bf16 bf16x8 __attribute__((ext_vector_type(8)));
typedef float f32x4 __attribute__((ext_vector_type(4)));

typedef __attribute__((address_space(3))) unsigned int lds_uint_t;
typedef __attribute__((address_space(1))) unsigned int glob_uint_t;

__device__ __forceinline__ void gload16(const void* g, void* l) {
  __builtin_amdgcn_global_load_lds((const glob_uint_t*)g, (lds_uint_t*)l, 16, 0, 0);
}

__device__ __forceinline__ f32x4 mfma16(bf16x8 a, bf16x8 b, f32x4 c) {
  return __builtin_amdgcn_mfma_f32_16x16x32_bf16(a, b, c, 0, 0, 0);
}

// ---------------- merged prep: f32->bf16 conv + 7 weight transposes, one dispatch ----------------
__device__ __forceinline__ void tconv_tile(const float* __restrict__ in, bf16_t* __restrict__ out,
                                           int R, int C, int c0, int r0, bf16_t* t, int tid) {
#pragma unroll
  for (int it = 0; it < 4; it++) {
    int c = tid + it * 256;
    int row = c >> 4, ch = c & 15;
    f32x4 v = *(const f32x4*)(in + (size_t)(r0 + row) * C + c0 + ch * 4);
#pragma unroll
    for (int j = 0; j < 4; j++) t[(ch * 4 + j) * 72 + row] = (bf16_t)v[j];
  }
  __syncthreads();
#pragma unroll
  for (int it = 0; it < 2; it++) {
    int c = tid + it * 256;
    int oc = c >> 3, ch = c & 7;
    bf16x8 v = *(const bf16x8*)(t + oc * 72 + ch * 8);
    *(bf16x8*)(out + (size_t)(c0 + oc) * R + r0 + ch * 8) = v;
  }
}

__global__ __launch_bounds__(256) void prep_k(const float* __restrict__ hs, bf16_t* __restrict__ hs_bf,
                                              const float* __restrict__ Wq, const float* __restrict__ Wk,
                                              const float* __restrict__ Wg, const float* __restrict__ Wv,
                                              const float* __restrict__ Wo, const float* __restrict__ Wqe,
                                              const float* __restrict__ Wke, bf16_t* __restrict__ WcatT,
                                              bf16_t* __restrict__ WoT, bf16_t* __restrict__ WqeT,
                                              bf16_t* __restrict__ WkeT) {
  __shared__ __align__(16) bf16_t t[64 * 72];
  const int blk = blockIdx.x;
  const int tid = threadIdx.x;
  if (blk < 2048) {
    int i = blk * 256 + tid;
    f32x4 a = *(const f32x4*)(hs + (size_t)i * 8);
    f32x4 b = *(const f32x4*)(hs + (size_t)i * 8 + 4);
    bf16x8 o;
    o[0] = (bf16_t)a[0]; o[1] = (bf16_t)a[1]; o[2] = (bf16_t)a[2]; o[3] = (bf16_t)a[3];
    o[4] = (bf16_t)b[0]; o[5] = (bf16_t)b[1]; o[6] = (bf16_t)b[2]; o[7] = (bf16_t)b[3];
    *(bf16x8*)(hs_bf + (size_t)i * 8) = o;
  } else if (blk < 3072) {
    int tt = blk - 2048;
    tconv_tile(Wq, WcatT, 2048, 2048, (tt & 31) * 64, (tt >> 5) * 64, t, tid);
  } else if (blk < 4096) {
    int tt = blk - 3072;
    tconv_tile(Wk, WcatT + 2048 * 2048, 2048, 2048, (tt & 31) * 64, (tt >> 5) * 64, t, tid);
  } else if (blk < 6144) {
    int tt = blk - 4096;
    tconv_tile(Wg, WcatT + 4096 * 2048, 2048, 4096, (tt & 63) * 64, (tt >> 6) * 64, t, tid);
  } else if (blk < 8192) {
    int tt = blk - 6144;
    tconv_tile(Wv, WcatT + 8192 * 2048, 2048, 4096, (tt & 63) * 64, (tt >> 6) * 64, t, tid);
  } else if (blk < 10240) {
    int tt = blk - 8192;
    tconv_tile(Wo, WoT, 4096, 2048, (tt & 31) * 64, (tt >> 5) * 64, t, tid);
  } else if (blk < 11008) {
    int tt = blk - 10240;
    int x = tt % 24, y = (tt / 24) & 3, z = tt / 96;
    tconv_tile(Wqe + (size_t)z * 393216, WqeT + (size_t)z * 393216, 256, 1536, x * 64, y * 64, t, tid);
  } else {
    int tt = blk - 11008;
    int x = tt % 24, y = (tt / 24) & 3, z = tt / 96;
    tconv_tile(Wke + (size_t)z * 393216, WkeT + (size_t)z * 393216, 256, 1536, x * 64, y * 64, t, tid);
  }
}

// ---------------- Wfused[kk][h*4+n] = sum_d Wq[kk][h*256+d] * Wgate[d][n] (fp32) ----------------
__global__ __launch_bounds__(256) void wfuse_k(const float* __restrict__ Wq, const float* __restrict__ Wgate,
                                               float* __restrict__ Wf) {
  __shared__ float wg[1024];
  const int tid = threadIdx.x;
  for (int i = tid; i < 1024; i += 256) wg[i] = Wgate[i];
  __syncthreads();
  const int kk = blockIdx.x * 64 + (tid & 63);
  const int oid = tid >> 6;
  float acc[8] = {0, 0, 0, 0, 0, 0, 0, 0};
  const float* wr = Wq + (size_t)kk * 2048;
#pragma unroll
  for (int half = 0; half < 2; half++) {
    const int h = oid * 2 + half;
    const float* seg = wr + h * 256;
    for (int d = 0; d < 256; d += 4) {
      f32x4 q4 = *(const f32x4*)(seg + d);
#pragma unroll
      for (int n = 0; n < 4; n++) {
        acc[half * 4 + n] += q4[0] * wg[(d + 0) * 4 + n] + q4[1] * wg[(d + 1) * 4 + n] +
                             q4[2] * wg[(d + 2) * 4 + n] + q4[3] * wg[(d + 3) * 4 + n];
      }
    }
  }
#pragma unroll
  for (int jj = 0; jj < 8; jj++) Wf[(size_t)kk * 32 + oid * 8 + jj] = acc[jj];
}

// ---------------- logits[bt][32] = hs[bt] @ Wfused (fp32) ----------------
__global__ __launch_bounds__(256) void logits_k(const float* __restrict__ hs, const float* __restrict__ Wf,
                                                float* __restrict__ lg) {
  __shared__ __align__(16) float hrow[2048];
  __shared__ float red[8][32];
  const int bt = blockIdx.x;
  const int tid = threadIdx.x;
  const float* src = hs + (size_t)bt * 2048;
  for (int i = tid; i < 512; i += 256) *(f32x4*)&hrow[i * 4] = *(const f32x4*)(src + i * 4);
  __syncthreads();
  const int j = tid & 31, part = tid >> 5;
  float acc = 0.f;
  for (int kk = part * 256; kk < part * 256 + 256; kk++) acc += hrow[kk] * Wf[(size_t)kk * 32 + j];
  red[part][j] = acc;
  __syncthreads();
  if (tid < 32) {
    float s = 0.f;
#pragma unroll
    for (int p = 0; p < 8; p++) s += red[p][tid];
    lg[(size_t)bt * 32 + tid] = s;
  }
}

// ---------------- routing: softmax over 4, top-2, weights -> rw[r][b][h][t] (fp32) ----------------
__global__ __launch_bounds__(256) void routing_k(const float* __restrict__ lg, float* __restrict__ rw) {
  int gid = blockIdx.x * 256 + threadIdx.x;
  if (gid >= 16384) return;
  const int h = gid >> 11;
  const int bt = gid & 2047;
  const int b = bt >> 10, tt = bt & 1023;
  f32x4 l = *(const f32x4*)(lg + (size_t)bt * 32 + h * 4);
  float mx = fmaxf(fmaxf(l[0], l[1]), fmaxf(l[2], l[3]));
  float e0 = __expf(l[0] - mx), e1 = __expf(l[1] - mx), e2 = __expf(l[2] - mx), e3 = __expf(l[3] - mx);
  float den = e0 + e1 + e2 + e3;
  float s[4] = {e0 / den, e1 / den, e2 / den, e3 / den};
  int i1 = 0;
#pragma unroll
  for (int i = 1; i < 4; i++) if (s[i] > s[i1]) i1 = i;
  int i2 = (i1 == 0) ? 1 : 0;
#pragma unroll
  for (int i = 0; i < 4; i++) if (i != i1 && s[i] > s[i2]) i2 = i;
  float sw = s[i1] + s[i2];
  float w1 = s[i1] / sw, w2 = s[i2] / sw;
  float tot = 1.0f + w1 + w2;
  float o[6] = {0.5f / tot, 0.5f / tot, 0.f, 0.f, 0.f, 0.f};
  o[2 + i1] = w1 / tot;
  o[2 + i2] = w2 / tot;
#pragma unroll
  for (int r = 0; r < 6; r++) rw[(size_t)((r * 2 + b) * 8 + h) * 1024 + tt] = o[r];
}

// ---------------- build compacted active-key index lists per (rr,bh) (deterministic scan) --------
__global__ __launch_bounds__(256) void idx_k(const float* __restrict__ rw, int* __restrict__ kidx,
                                             float* __restrict__ maskg, int2* __restrict__ kn) {
  __shared__ int wsum[4];
  const int z = blockIdx.x;            // rr*16 + bh
  const int rr = z >> 4, bh = z & 15;
  const int b = bh >> 3, h = bh & 7;
  const float* rwp = rw + (size_t)(((rr + 2) * 2 + b) * 8 + h) * 1024;
  const int tid = threadIdx.x;
  const int lane = tid & 63, wv = tid >> 6;
  int act[4];
  int c = 0;
#pragma unroll
  for (int j = 0; j < 4; j++) { act[j] = (rwp[tid * 4 + j] != 0.f) ? 1 : 0; c += act[j]; }
  int s = c;
  for (int o = 1; o < 64; o <<= 1) { int t = __shfl_up(s, o, 64); if (lane >= o) s += t; }
  if (lane == 63) wsum[wv] = s;
  __syncthreads();
  int base = 0;
  for (int wi = 0; wi < wv; wi++) base += wsum[wi];
  int excl = base + s - c;
  int Na = wsum[0] + wsum[1] + wsum[2] + wsum[3];
  int* kout = kidx + (size_t)z * 1088;
  float* mout = maskg + (size_t)z * 1088;
  int o = excl;
#pragma unroll
  for (int j = 0; j < 4; j++)
    if (act[j]) { kout[o] = tid * 4 + j; mout[o] = 1.f; o++; }
  for (int i = Na + tid; i < 1088; i += 256) { kout[i] = 0; mout[i] = 0.f; }
  if (tid == 0) kn[z] = make_int2(Na, (Na + 63) & ~63);
}

// ---------------- merged: transpose V (dense) + gather+transpose V (routed) ----------------
__global__ __launch_bounds__(256) void tvvg_k(const bf16_t* __restrict__ qkg, const int* __restrict__ kidx,
                                              const int2* __restrict__ kn, bf16_t* __restrict__ Vt,
                                              bf16_t* __restrict__ Vg) {
  __shared__ __align__(16) bf16_t t[64 * 72];
  __shared__ int idx[64];
  const int blk = blockIdx.x;
  const int tid = threadIdx.x;
  if (blk < 2048) {
    const int x = blk & 15, y = (blk >> 4) & 7, bh = blk >> 7;
    const int tt0 = x * 64, dv0 = y * 64;
    const int b = bh >> 3, h = bh & 7;
    const bf16_t* src = qkg + (size_t)(b * 1024 + tt0) * 12288 + 8192 + h * 512 + dv0;
#pragma unroll
    for (int it = 0; it < 2; it++) {
      int c = tid + it * 256;
      int row = c >> 3, ch = c & 7;
      bf16x8 x8 = *(const bf16x8*)(src + (size_t)row * 12288 + ch * 8);
#pragma unroll
      for (int j = 0; j < 8; j++) t[(ch * 8 + j) * 72 + row] = x8[j];
    }
    __syncthreads();
    bf16_t* dst = Vt + (size_t)bh * 524288 + (size_t)dv0 * 1024 + tt0;
#pragma unroll
    for (int it = 0; it < 2; it++) {
      int c = tid + it * 256;
      int od = c >> 3, ch = c & 7;
      bf16x8 x8 = *(const bf16x8*)(t + od * 72 + ch * 8);
      *(bf16x8*)(dst + (size_t)od * 1024 + ch * 8) = x8;
    }
  } else {
    const int t2 = blk - 2048;
    const int x = t2 & 15, y = (t2 >> 4) & 7, z = t2 >> 7;
    const int rr = z >> 4, bh = z & 15;
    const int b = bh >> 3, h = bh & 7;
    int2 k = kn[z];
    const int s0 = x * 64;
    if (s0 >= k.y) return;
    const int dv0 = y * 64;
    if (tid < 64) idx[tid] = kidx[(size_t)z * 1088 + s0 + tid];
    __syncthreads();
    int base = 0;
    for (int r2 = 0; r2 < rr; r2++) base += kn[r2 * 16 + bh].y;
#pragma unroll
    for (int it = 0; it < 2; it++) {
      int cc = tid + it * 256;
      int row = cc >> 3, ch = cc & 7;
      const bf16_t* src = qkg + (size_t)(b * 1024 + idx[row]) * 12288 + 8192 + h * 512 + dv0 + ch * 8;
      bf16x8 x8 = *(const bf16x8*)src;
#pragma unroll
      for (int j = 0; j < 8; j++) t[(ch * 8 + j) * 72 + row] = x8[j];
    }
    __syncthreads();
    bf16_t* dst = Vg + (size_t)(bh * 512 + dv0) * 2304 + base + s0;
#pragma unroll
    for (int it = 0; it < 2; it++) {
      int cc = tid + it * 256;
      int od = cc >> 3, ch = cc & 7;
      bf16x8 x8 = *(const bf16x8*)(t + od * 72 + ch * 8);
      *(bf16x8*)(dst + (size_t)od * 2304 + ch * 8) = x8;
    }
  }
}

// ---------------- bf16 GEMM, 128x128 tile, BK=64 (A row-major, B stored transposed [N][K]) ----------
template <int MODE>
__global__ __launch_bounds__(256) void gemm_bt(const bf16_t* __restrict__ A, const bf16_t* __restrict__ B,
                                               void* __restrict__ Cp, int K, int lda, int ldb, int ldc) {
  __shared__ __align__(16) bf16_t lsA[128 * 64];
  __shared__ __align__(16) bf16_t lsB[128 * 64];
  const int tid = threadIdx.x;
  const int lane = tid & 63, wv = tid >> 6;
  const int lrow = lane & 15, lgrp = lane >> 4;
  const int wr = wv >> 1, wc = wv & 1;
  const int bn = blockIdx.x * 128, bm = blockIdx.y * 128;

  f32x4 zero = {0.f, 0.f, 0.f, 0.f};
  f32x4 acc[4][4];
#pragma unroll
  for (int i = 0; i < 4; i++)
#pragma unroll
    for (int j = 0; j < 4; j++) acc[i][j] = zero;

  for (int k0 = 0; k0 < K; k0 += 64) {
    __syncthreads();
#pragma unroll
    for (int it = 0; it < 4; it++) {
      int c = tid + it * 256;
      int row = c >> 3, coff = (c & 7) * 16;
      gload16((const char*)A + ((size_t)(bm + row) * lda + k0) * 2 + coff, (char*)lsA + row * 128 + coff);
      gload16((const char*)B + ((size_t)(bn + row) * ldb + k0) * 2 + coff, (char*)lsB + row * 128 + coff);
    }
    __syncthreads();
#pragma unroll
    for (int kk = 0; kk < 2; kk++) {
      bf16x8 af[4], bfr[4];
#pragma unroll
      for (int m4 = 0; m4 < 4; m4++)
        af[m4] = *(const bf16x8*)((const char*)lsA + (wr * 64 + m4 * 16 + lrow) * 128 + kk * 64 + lgrp * 16);
#pragma unroll
      for (int n4 = 0; n4 < 4; n4++)
        bfr[n4] = *(const bf16x8*)((const char*)lsB + (wc * 64 + n4 * 16 + lrow) * 128 + kk * 64 + lgrp * 16);
#pragma unroll
      for (int m4 = 0; m4 < 4; m4++)
#pragma unroll
        for (int n4 = 0; n4 < 4; n4++) acc[m4][n4] = mfma16(af[m4], bfr[n4], acc[m4][n4]);
    }
  }
#pragma unroll
  for (int m4 = 0; m4 < 4; m4++) {
#pragma unroll
    for (int i = 0; i < 4; i++) {
      const int row = bm + wr * 64 + m4 * 16 + lgrp * 4 + i;
#pragma unroll
      for (int n4 = 0; n4 < 4; n4++) {
        const int col = bn + wc * 64 + n4 * 16 + lrow;
        float v = acc[m4][n4][i];
        if constexpr (MODE == 0) {
          ((bf16_t*)Cp)[(size_t)row * ldc + col] = (bf16_t)v;
        } else {
          ((float*)Cp)[(size_t)row * ldc + col] = v;
        }
      }
    }
  }
}

// ---------------- 128x64-tile GEMM (f32 out) for the output projection: 512 blocks ----------------
__global__ __launch_bounds__(256) void gemm_n64(const bf16_t* __restrict__ A, const bf16_t* __restrict__ B,
                                                float* __restrict__ C, int K, int lda, int ldb, int ldc) {
  __shared__ __align__(16) bf16_t lsA[128 * 64];
  __shared__ __align__(16) bf16_t lsB[64 * 64];
  const int tid = threadIdx.x;
  const int lane = tid & 63, wr = tid >> 6;
  const int lrow = lane & 15, lgrp = lane >> 4;
  const int bn = blockIdx.x * 64, bm = blockIdx.y * 128;

  f32x4 zero = {0.f, 0.f, 0.f, 0.f};
  f32x4 acc[2][4];
#pragma unroll
  for (int i = 0; i < 2; i++)
#pragma unroll
    for (int j = 0; j < 4; j++) acc[i][j] = zero;

  for (int k0 = 0; k0 < K; k0 += 64) {
    __syncthreads();
#pragma unroll
    for (int it = 0; it < 4; it++) {
      int c = tid + it * 256;
      int row = c >> 3, coff = (c & 7) * 16;
      gload16((const char*)A + ((size_t)(bm + row) * lda + k0) * 2 + coff, (char*)lsA + row * 128 + coff);
    }
#pragma unroll
    for (int it = 0; it < 2; it++) {
      int c = tid + it * 256;
      int row = c >> 3, coff = (c & 7) * 16;
      gload16((const char*)B + ((size_t)(bn + row) * ldb + k0) * 2 + coff, (char*)lsB + row * 128 + coff);
    }
    __syncthreads();
#pragma unroll
    for (int kk = 0; kk < 2; kk++) {
      bf16x8 af[2], bfr[4];
#pragma unroll
      for (int m2 = 0; m2 < 2; m2++)
        af[m2] = *(const bf16x8*)((const char*)lsA + (wr * 32 + m2 * 16 + lrow) * 128 + kk * 64 + lgrp * 16);
#pragma unroll
      for (int n4 = 0; n4 < 4; n4++)
        bfr[n4] = *(const bf16x8*)((const char*)lsB + (n4 * 16 + lrow) * 128 + kk * 64 + lgrp * 16);
#pragma unroll
      for (int m2 = 0; m2 < 2; m2++)
#pragma unroll
        for (int n4 = 0; n4 < 4; n4++) acc[m2][n4] = mfma16(af[m2], bfr[n4], acc[m2][n4]);
    }
  }
#pragma unroll
  for (int m2 = 0; m2 < 2; m2++) {
#pragma unroll
    for (int i = 0; i < 4; i++) {
      const int row = bm + wr * 32 + m2 * 16 + lgrp * 4 + i;
#pragma unroll
      for (int n4 = 0; n4 < 4; n4++) {
        C[(size_t)row * ldc + bn + n4 * 16 + lrow] = acc[m2][n4][i];
      }
    }
  }
}

// ---------------- merged expert-expansion GEMM: z in [0,16): sel=z>>3 (0=q,1=k), head=z&7 -----------
__global__ __launch_bounds__(256) void gemm_exp(const bf16_t* __restrict__ qkg, const bf16_t* __restrict__ Wqe,
                                                const bf16_t* __restrict__ Wke, bf16_t* __restrict__ qeB,
                                                bf16_t* __restrict__ keB) {
  const int z = blockIdx.z;
  const int sel = z >> 3, hh = z & 7;
  if (sel == 1 && blockIdx.x >= 4) return;
  __shared__ __align__(16) bf16_t lsA[128 * 64];
  __shared__ __align__(16) bf16_t lsB[128 * 64];
  const int tid = threadIdx.x;
  const int lane = tid & 63, wv = tid >> 6;
  const int lrow = lane & 15, lgrp = lane >> 4;
  const int wr = wv >> 1, wc = wv & 1;
  const int bn = blockIdx.x * 128, bm = blockIdx.y * 128;
  const bf16_t* A = qkg + sel * 2048 + hh * 256;
  const bf16_t* B = (sel ? Wke : Wqe) + (size_t)hh * 393216;
  bf16_t* C = sel ? keB : qeB;

  f32x4 zero = {0.f, 0.f, 0.f, 0.f};
  f32x4 acc[4][4];
#pragma unroll
  for (int i = 0; i < 4; i++)
#pragma unroll
    for (int j = 0; j < 4; j++) acc[i][j] = zero;

  for (int k0 = 0; k0 < 256; k0 += 64) {
    __syncthreads();
#pragma unroll
    for (int it = 0; it < 4; it++) {
      int c = tid + it * 256;
      int row = c >> 3, coff = (c & 7) * 16;
      gload16((const char*)A + ((size_t)(bm + row) * 12288 + k0) * 2 + coff, (char*)lsA + row * 128 + coff);
      gload16((const char*)B + ((size_t)(bn + row) * 256 + k0) * 2 + coff, (char*)lsB + row * 128 + coff);
    }
    __syncthreads();
#pragma unroll
    for (int kk = 0; kk < 2; kk++) {
      bf16x8 af[4], bfr[4];
#pragma unroll
      for (int m4 = 0; m4 < 4; m4++)
        af[m4] = *(const bf16x8*)((const char*)lsA + (wr * 64 + m4 * 16 + lrow) * 128 + kk * 64 + lgrp * 16);
#pragma unroll
      for (int n4 = 0; n4 < 4; n4++)
        bfr[n4] = *(const bf16x8*)((const char*)lsB + (wc * 64 + n4 * 16 + lrow) * 128 + kk * 64 + lgrp * 16);
#pragma unroll
      for (int m4 = 0; m4 < 4; m4++)
#pragma unroll
        for (int n4 = 0; n4 < 4; n4++) acc[m4][n4] = mfma16(af[m4], bfr[n4], acc[m4][n4]);
    }
  }
#pragma unroll
  for (int m4 = 0; m4 < 4; m4++) {
#pragma unroll
    for (int i = 0; i < 4; i++) {
      const int row = bm + wr * 64 + m4 * 16 + lgrp * 4 + i;
      const int bb = row >> 10, tt = row & 1023;
#pragma unroll
      for (int n4 = 0; n4 < 4; n4++) {
        const int col = bn + wc * 64 + n4 * 16 + lrow;
        const int rr = col >> 8, dd = col & 255;
        C[((size_t)((rr * 2 + bb) * 8 + hh) * 1024 + tt) * 256 + dd] = (bf16_t)acc[m4][n4][i];
      }
    }
  }
}

// ---------------- gathered K expert expansion: keG[z][slot][256], z = rr*16+bh ----------------
__global__ __launch_bounds__(256) void gemm_kg(const bf16_t* __restrict__ qkg, const bf16_t* __restrict__ Wke,
                                               const int* __restrict__ kidx, const int2* __restrict__ kn,
                                               bf16_t* __restrict__ keG) {
  const int z = blockIdx.z;
  const int rr = z >> 4, bh = z & 15;
  const int bm = blockIdx.y * 128;
  if (bm >= kn[z].y) return;
  __shared__ __align__(16) bf16_t lsA[128 * 64];
  __shared__ __align__(16) bf16_t lsB[128 * 64];
  __shared__ int sidx[128];
  const int b = bh >> 3, h = bh & 7;
  const int bn = blockIdx.x * 128;
  const int tid = threadIdx.x;
  const int lane = tid & 63, wv = tid >> 6;
  const int lrow = lane & 15, lgrp = lane >> 4;
  const int wr = wv >> 1, wc = wv & 1;
  if (tid < 128) sidx[tid] = kidx[(size_t)z * 1088 + bm + tid];
  const bf16_t* Abase = qkg + 2048 + h * 256;
  const bf16_t* B = Wke + (size_t)h * 393216 + (size_t)((rr + 2) * 256 + bn) * 256;

  f32x4 zero = {0.f, 0.f, 0.f, 0.f};
  f32x4 acc[4][4];
#pragma unroll
  for (int i = 0; i < 4; i++)
#pragma unroll
    for (int j = 0; j < 4; j++) acc[i][j] = zero;

  for (int k0 = 0; k0 < 256; k0 += 64) {
    __syncthreads();
#pragma unroll
    for (int it = 0; it < 4; it++) {
      int c = tid + it * 256;
      int row = c >> 3, coff = (c & 7) * 16;
      gload16((const char*)(Abase + ((size_t)(b * 1024 + sidx[row]) * 12288 + k0)) + coff,
              (char*)lsA + row * 128 + coff);
      gload16((const char*)B + ((size_t)row * 256 + k0) * 2 + coff, (char*)lsB + row * 128 + coff);
    }
    __syncthreads();
#pragma unroll
    for (int kk = 0; kk < 2; kk++) {
      bf16x8 af[4], bfr[4];
#pragma unroll
      for (int m4 = 0; m4 < 4; m4++)
        af[m4] = *(const bf16x8*)((const char*)lsA + (wr * 64 + m4 * 16 + lrow) * 128 + kk * 64 + lgrp * 16);
#pragma unroll
      for (int n4 = 0; n4 < 4; n4++)
        bfr[n4] = *(const bf16x8*)((const char*)lsB + (wc * 64 + n4 * 16 + lrow) * 128 + kk * 64 + lgrp * 16);
#pragma unroll
      for (int m4 = 0; m4 < 4; m4++)
#pragma unroll
        for (int n4 = 0; n4 < 4; n4++) acc[m4][n4] = mfma16(af[m4], bfr[n4], acc[m4][n4]);
    }
  }
#pragma unroll
  for (int m4 = 0; m4 < 4; m4++) {
#pragma unroll
    for (int i = 0; i < 4; i++) {
      const int row = bm + wr * 64 + m4 * 16 + lgrp * 4 + i;
#pragma unroll
      for (int n4 = 0; n4 < 4; n4++) {
        const int col = bn + wc * 64 + n4 * 16 + lrow;
        keG[((size_t)z * 1088 + row) * 256 + col] = (bf16_t)acc[m4][n4][i];
      }
    }
  }
}

// ---------------- fused masked attention: K read DIRECT from global/L2 (no K LDS) ----------------
// 512 blocks XCD-swizzled, 256 threads (4 waves x 16 q-rows), 2 blocks/CU.
// K fragment layout == ke/keG row layout, so QK B-frags load straight from L2 (XCD-resident).
// V stays gload_lds double-buffered; LDS traffic per block-tile drops ~2x (K was half of it).
__global__ __launch_bounds__(256, 2) void attn_k(const bf16_t* __restrict__ qe, const bf16_t* __restrict__ ke,
                                                 const bf16_t* __restrict__ keG, const bf16_t* __restrict__ Vt,
                                                 const float* __restrict__ rw, const bf16_t* __restrict__ g,
                                                 bf16_t* __restrict__ oc, const float* __restrict__ maskg,
                                                 const int2* __restrict__ kn, const bf16_t* __restrict__ Vg) {
  __shared__ __align__(16) bf16_t ldsV[2][256 * 32];   // [buf][row 64B], swz: off ^= ((row>>1)&3)<<4
  __shared__ __align__(16) bf16_t ldsP[4 * 16 * 40];   // per-wave 16 q x 32 keys, row-permuted

  const int f = (blockIdx.x & 7) * 64 + (blockIdx.x >> 3);
  const int qt = f & 15, dvh = (f >> 4) & 1, bh = f >> 5;

  const int tid = threadIdx.x;
  const int wv = tid >> 6, lane = tid & 63;
  const int lrow = lane & 15, lgrp = lane >> 4;
  const int b = bh >> 3, h = bh & 7;
  const int qw = qt * 64 + wv * 16;

  const char* vtb = (const char*)Vt + ((size_t)bh * 524288 + (size_t)dvh * 262144) * 2;

  f32x4 zero = {0.f, 0.f, 0.f, 0.f};
  f32x4 Otot[16];
#pragma unroll
  for (int n = 0; n < 16; n++) Otot[n] = zero;

  int cur = 0;
  for (int r = 0; r < 6; r++) {
    const size_t rbh = (size_t)((r * 2 + b) * 8 + h);
    const bf16_t* qbase = qe + rbh * 262144;
    const float* rwb = rw + rbh * 1024;

    int nkt = 32;
    float lpinit = 0.f;
    const float* mgp = nullptr;
    const char* vgb = vtb;
    size_t vstride = 2048;
    const char* kbase = (const char*)ke + rbh * 524288;
    const bool routed = (r >= 2);
    if (routed) {
      const int rr = r - 2;
      int2 kkn = kn[rr * 16 + bh];
      nkt = kkn.y >> 5;
      lpinit = (float)(1024 - kkn.x) * 0.0625f;
      int basep = 0;
      for (int r2 = 0; r2 < rr; r2++) basep += kn[r2 * 16 + bh].y;
      vgb = (const char*)Vg + ((size_t)(bh * 512 + dvh * 256) * 2304 + basep) * 2;
      vstride = 4608;
      mgp = maskg + (size_t)(rr * 16 + bh) * 1088;
      kbase = (const char*)keG + (size_t)(rr * 16 + bh) * 557056;   // 1088*512 bytes
    }
    if (nkt == 0) continue;

    bf16x8 qf[8];
#pragma unroll
    for (int c = 0; c < 8; c++)
      qf[c] = *(const bf16x8*)(qbase + (size_t)(qw + lrow) * 256 + c * 32 + lgrp * 8);
    float rwq[4];
#pragma unroll
    for (int i = 0; i < 4; i++) rwq[i] = rwb[qw + lgrp * 4 + i];

    float Lp[4] = {lpinit, lpinit, lpinit, lpinit};
    f32x4 accO[16];
#pragma unroll
    for (int n = 0; n < 16; n++) accO[n] = zero;

    auto issue_v = [&](int kt, int buf) {
      char* lv = (char*)ldsV[buf];
      const char* vb = vgb + (size_t)kt * 64;
#pragma unroll
      for (int it = 0; it < 4; it++) {
        int p = (wv * 4 + it) * 1024 + (lane << 4);
        int row = p >> 6, off = p & 63;
        gload16(vb + (size_t)row * vstride + (off ^ (((row >> 1) & 3) << 4)), lv + p);
      }
    };

    issue_v(0, cur);
    for (int kt = 0; kt < nkt; kt++) {
      asm volatile("s_waitcnt vmcnt(0) lgkmcnt(0)" ::: "memory");
      __syncthreads();
      if (kt + 1 < nkt) issue_v(kt + 1, cur ^ 1);
      const char* lV = (const char*)ldsV[cur];
      float mg0 = 1.f, mg1 = 1.f;
      if (routed) { mg0 = mgp[kt * 32 + lrow]; mg1 = mgp[kt * 32 + 16 + lrow]; }

      // S = Q K^T — K B-frags loaded DIRECTLY from global (row layout == frag layout)
      const char* krow0 = kbase + (size_t)(kt * 32 + lrow) * 512 + lgrp * 16;
      const char* krow1 = kbase + (size_t)(kt * 32 + 16 + lrow) * 512 + lgrp * 16;
      f32x4 sac0 = zero, sac1 = zero;
      __builtin_amdgcn_s_setprio(1);
#pragma unroll
      for (int c = 0; c < 8; c++) {
        bf16x8 k0 = *(const bf16x8*)(krow0 + c * 64);
        bf16x8 k1 = *(const bf16x8*)(krow1 + c * 64);
        sac0 = mfma16(qf[c], k0, sac0);
        sac1 = mfma16(qf[c], k1, sac1);
      }
      __builtin_amdgcn_s_setprio(0);
      // fixed-M softmax; gathered pad slots have mg=0 -> P=0, denom+=0
      bf16_t* pb = ldsP + wv * 640;
#pragma unroll
      for (int i = 0; i < 4; i++) {
        float p0 = mg0 * __expf(sac0[i] * 0.0625f);
        float p1 = mg1 * __expf(sac1[i] * 0.0625f);
        pb[(i * 4 + lgrp) * 40 + lrow] = (bf16_t)p0;
        pb[(i * 4 + lgrp) * 40 + 16 + lrow] = (bf16_t)p1;
        Lp[i] += p0 + p1;
      }
      bf16x8 pa = *(const bf16x8*)(pb + ((lrow & 3) * 4 + (lrow >> 2)) * 40 + lgrp * 8);
      __builtin_amdgcn_s_setprio(1);
#pragma unroll
      for (int n = 0; n < 16; n++) {
        int row = n * 16 + lrow;
        int col = (lgrp * 16) ^ (((row >> 1) & 3) << 4);
        bf16x8 vf = *(const bf16x8*)(lV + (size_t)row * 64 + col);
        accO[n] = mfma16(pa, vf, accO[n]);
      }
      __builtin_amdgcn_s_setprio(0);
      cur ^= 1;
    }  // kt
#pragma unroll
    for (int i = 0; i < 4; i++) {
      float v = Lp[i];
      v += __shfl_xor(v, 1, 16);
      v += __shfl_xor(v, 2, 16);
      v += __shfl_xor(v, 4, 16);
      v += __shfl_xor(v, 8, 16);
      float inv = rwq[i] / v;
#pragma unroll
      for (int n = 0; n < 16; n++) Otot[n][i] += accO[n][i] * inv;
    }
  }  // r

  // epilogue: o * silu(g) -> O_comb bf16 (g = qkg cols [4096,8192), row stride 12288)
#pragma unroll
  for (int i = 0; i < 4; i++) {
    const size_t grow = ((size_t)(b * 1024 + qw + lgrp * 4 + i)) * 12288 + 4096 + h * 512 + dvh * 256;
    const size_t orow = ((size_t)(b * 1024 + qw + lgrp * 4 + i)) * 4096 + h * 512 + dvh * 256;
#pragma unroll
    for (int n = 0; n < 16; n++) {
      float gv = (float)g[grow + n * 16 + lrow];
      float sg = gv / (1.f + __expf(-gv));
      oc[orow + n * 16 + lrow] = (bf16_t)(Otot[n][i] * sg);
    }
  }
}

// =====================================================================================
extern "C" void kernel_launch(void* const* d_in, const int* in_sizes, int n_in,
                              void* d_out, int out_size, void* d_ws, size_t ws_size,
                              hipStream_t stream) {
  const float* hs  = (const float*)d_in[0];
  const float* Wq  = (const float*)d_in[1];
  const float* Wk  = (const float*)d_in[2];
  const float* Wv  = (const float*)d_in[3];
  const float* Wqe = (const float*)d_in[4];
  const float* Wke = (const float*)d_in[5];
  const float* Wgt = (const float*)d_in[6];
  const float* Wg  = (const float*)d_in[7];
  const float* Wo  = (const float*)d_in[8];
  float* out = (float*)d_out;

  // Liveness-aware workspace layout; peak footprint ~252 MiB.
  const size_t MB = 1024 * 1024;
  char* w = (char*)d_ws;
  bf16_t* hs_bf = (bf16_t*)(w + 0 * MB);    // 8MB, dead after mega-proj
  bf16_t* WcatT = (bf16_t*)(w + 8 * MB);    // 48MB, dead after proj
  bf16_t* qeB   = (bf16_t*)(w + 0 * MB);    // 48MB, written AFTER proj (overlays)
  bf16_t* WoT   = (bf16_t*)(w + 56 * MB);   // 16MB
  bf16_t* WqeT  = (bf16_t*)(w + 72 * MB);   // 6MB
  bf16_t* WkeT  = (bf16_t*)(w + 78 * MB);   // 6MB
  bf16_t* qkg   = (bf16_t*)(w + 84 * MB);   // 48MB: [2048][12288] = q|k|g|v
  bf16_t* Vt    = (bf16_t*)(w + 132 * MB);  // 16MB
  bf16_t* keB   = (bf16_t*)(w + 148 * MB);  // 16MB (shared experts only)
  bf16_t* keG   = (bf16_t*)(w + 164 * MB);  // 34MB: [64][1088][256]
  bf16_t* ocB   = (bf16_t*)(w + 198 * MB);  // 16MB
  bf16_t* VgB   = (bf16_t*)(w + 214 * MB);  // 36MB: [16][512][2304]
  float*  Wf    = (float*)(w + 250 * MB);               // 256KB
  float*  lg    = (float*)(w + 250 * MB + 262144);      // 256KB
  float*  rwB   = (float*)(w + 250 * MB + 524288);      // 384KB
  int*    kidxB = (int*)(w + 251 * MB);                 // 272KB
  float*  maskgB= (float*)(w + 251 * MB + 524288);      // 272KB
  int2*   knB   = (int2*)(w + 251 * MB + 1048576);      // 512B
  (void)ws_size; (void)in_sizes; (void)n_in; (void)out_size;

  // merged conversions/transposes (1 dispatch)
  prep_k<<<11776, 256, 0, stream>>>(hs, hs_bf, Wq, Wk, Wg, Wv, Wo, Wqe, Wke, WcatT, WoT, WqeT, WkeT);

  // fp32 routing path + compaction
  wfuse_k<<<32, 256, 0, stream>>>(Wq, Wgt, Wf);
  logits_k<<<2048, 256, 0, stream>>>(hs, Wf, lg);
  routing_k<<<64, 256, 0, stream>>>(lg, rwB);
  idx_k<<<64, 256, 0, stream>>>(rwB, kidxB, maskgB, knB);

  // single mega projection q|k|g|v (N=12288)
  gemm_bt<0><<<dim3(96, 16, 1), 256, 0, stream>>>(hs_bf, WcatT, qkg, 2048, 2048, 2048, 12288);

  // merged V transpose (dense) + V gather (routed), 1 dispatch
  tvvg_k<<<10240, 256, 0, stream>>>(qkg, kidxB, knB, Vt, VgB);

  // expert expansions: qe dense (all), ke dense (shared only), keG gathered (routed)
  gemm_exp<<<dim3(12, 16, 16), 256, 0, stream>>>(qkg, WqeT, WkeT, qeB, keB);
  gemm_kg<<<dim3(2, 8, 64), 256, 0, stream>>>(qkg, WkeT, kidxB, knB, keG);

  // fused attention: K direct-from-L2, V via LDS
  attn_k<<<512, 256, 0, stream>>>(qeB, keB, keG, Vt, rwB, qkg, ocB, maskgB, knB, VgB);

  // output projection (fp32 out, 128x64 tiles -> 512 blocks)
  gemm_n64<<<dim3(32, 16, 1), 256, 0, stream>>>(ocB, WoT, out, 4096, 4096, 4096, 2048);
}

// Round 15
// 644.549 us; speedup vs baseline: 1.5356x; 1.5356x over previous
//
#include <hip/hip_runtime.h>
#include <hip/hip_bf16.h>
#include <cstdint>
#include <cstddef>

// H=8 D=256 R=6 S=2 K=2 EV=2, HID=2048, DV=512, b=2, t=1024
typedef __bf16 bf16_t;
typedef __bf16 bf16x8 __attribute__((ext_vector_type(8)));
typedef float f32x4 __attribute__((ext_vector_type(4)));

typedef __attribute__((address_space(3))) unsigned int lds_uint_t;
typedef __attribute__((address_space(1))) unsigned int glob_uint_t;

__device__ __forceinline__ void gload16(const void* g, void* l) {
  __builtin_amdgcn_global_load_lds((const glob_uint_t*)g, (lds_uint_t*)l, 16, 0, 0);
}

__device__ __forceinline__ f32x4 mfma16(bf16x8 a, bf16x8 b, f32x4 c) {
  return __builtin_amdgcn_mfma_f32_16x16x32_bf16(a, b, c, 0, 0, 0);
}

// ---------------- merged prep: f32->bf16 conv + 7 weight transposes, one dispatch ----------------
__device__ __forceinline__ void tconv_tile(const float* __restrict__ in, bf16_t* __restrict__ out,
                                           int R, int C, int c0, int r0, bf16_t* t, int tid) {
#pragma unroll
  for (int it = 0; it < 4; it++) {
    int c = tid + it * 256;
    int row = c >> 4, ch = c & 15;
    f32x4 v = *(const f32x4*)(in + (size_t)(r0 + row) * C + c0 + ch * 4);
#pragma unroll
    for (int j = 0; j < 4; j++) t[(ch * 4 + j) * 72 + row] = (bf16_t)v[j];
  }
  __syncthreads();
#pragma unroll
  for (int it = 0; it < 2; it++) {
    int c = tid + it * 256;
    int oc = c >> 3, ch = c & 7;
    bf16x8 v = *(const bf16x8*)(t + oc * 72 + ch * 8);
    *(bf16x8*)(out + (size_t)(c0 + oc) * R + r0 + ch * 8) = v;
  }
}

__global__ __launch_bounds__(256) void prep_k(const float* __restrict__ hs, bf16_t* __restrict__ hs_bf,
                                              const float* __restrict__ Wq, const float* __restrict__ Wk,
                                              const float* __restrict__ Wg, const float* __restrict__ Wv,
                                              const float* __restrict__ Wo, const float* __restrict__ Wqe,
                                              const float* __restrict__ Wke, bf16_t* __restrict__ WcatT,
                                              bf16_t* __restrict__ WoT, bf16_t* __restrict__ WqeT,
                                              bf16_t* __restrict__ WkeT) {
  __shared__ __align__(16) bf16_t t[64 * 72];
  const int blk = blockIdx.x;
  const int tid = threadIdx.x;
  if (blk < 2048) {
    int i = blk * 256 + tid;
    f32x4 a = *(const f32x4*)(hs + (size_t)i * 8);
    f32x4 b = *(const f32x4*)(hs + (size_t)i * 8 + 4);
    bf16x8 o;
    o[0] = (bf16_t)a[0]; o[1] = (bf16_t)a[1]; o[2] = (bf16_t)a[2]; o[3] = (bf16_t)a[3];
    o[4] = (bf16_t)b[0]; o[5] = (bf16_t)b[1]; o[6] = (bf16_t)b[2]; o[7] = (bf16_t)b[3];
    *(bf16x8*)(hs_bf + (size_t)i * 8) = o;
  } else if (blk < 3072) {
    int tt = blk - 2048;
    tconv_tile(Wq, WcatT, 2048, 2048, (tt & 31) * 64, (tt >> 5) * 64, t, tid);
  } else if (blk < 4096) {
    int tt = blk - 3072;
    tconv_tile(Wk, WcatT + 2048 * 2048, 2048, 2048, (tt & 31) * 64, (tt >> 5) * 64, t, tid);
  } else if (blk < 6144) {
    int tt = blk - 4096;
    tconv_tile(Wg, WcatT + 4096 * 2048, 2048, 4096, (tt & 63) * 64, (tt >> 6) * 64, t, tid);
  } else if (blk < 8192) {
    int tt = blk - 6144;
    tconv_tile(Wv, WcatT + 8192 * 2048, 2048, 4096, (tt & 63) * 64, (tt >> 6) * 64, t, tid);
  } else if (blk < 10240) {
    int tt = blk - 8192;
    tconv_tile(Wo, WoT, 4096, 2048, (tt & 31) * 64, (tt >> 5) * 64, t, tid);
  } else if (blk < 11008) {
    int tt = blk - 10240;
    int x = tt % 24, y = (tt / 24) & 3, z = tt / 96;
    tconv_tile(Wqe + (size_t)z * 393216, WqeT + (size_t)z * 393216, 256, 1536, x * 64, y * 64, t, tid);
  } else {
    int tt = blk - 11008;
    int x = tt % 24, y = (tt / 24) & 3, z = tt / 96;
    tconv_tile(Wke + (size_t)z * 393216, WkeT + (size_t)z * 393216, 256, 1536, x * 64, y * 64, t, tid);
  }
}

// ---------------- Wfused[kk][h*4+n] = sum_d Wq[kk][h*256+d] * Wgate[d][n] (fp32) ----------------
__global__ __launch_bounds__(256) void wfuse_k(const float* __restrict__ Wq, const float* __restrict__ Wgate,
                                               float* __restrict__ Wf) {
  __shared__ float wg[1024];
  const int tid = threadIdx.x;
  for (int i = tid; i < 1024; i += 256) wg[i] = Wgate[i];
  __syncthreads();
  const int kk = blockIdx.x * 64 + (tid & 63);
  const int oid = tid >> 6;
  float acc[8] = {0, 0, 0, 0, 0, 0, 0, 0};
  const float* wr = Wq + (size_t)kk * 2048;
#pragma unroll
  for (int half = 0; half < 2; half++) {
    const int h = oid * 2 + half;
    const float* seg = wr + h * 256;
    for (int d = 0; d < 256; d += 4) {
      f32x4 q4 = *(const f32x4*)(seg + d);
#pragma unroll
      for (int n = 0; n < 4; n++) {
        acc[half * 4 + n] += q4[0] * wg[(d + 0) * 4 + n] + q4[1] * wg[(d + 1) * 4 + n] +
                             q4[2] * wg[(d + 2) * 4 + n] + q4[3] * wg[(d + 3) * 4 + n];
      }
    }
  }
#pragma unroll
  for (int jj = 0; jj < 8; jj++) Wf[(size_t)kk * 32 + oid * 8 + jj] = acc[jj];
}

// ---------------- logits[bt][32] = hs[bt] @ Wfused (fp32) ----------------
__global__ __launch_bounds__(256) void logits_k(const float* __restrict__ hs, const float* __restrict__ Wf,
                                                float* __restrict__ lg) {
  __shared__ __align__(16) float hrow[2048];
  __shared__ float red[8][32];
  const int bt = blockIdx.x;
  const int tid = threadIdx.x;
  const float* src = hs + (size_t)bt * 2048;
  for (int i = tid; i < 512; i += 256) *(f32x4*)&hrow[i * 4] = *(const f32x4*)(src + i * 4);
  __syncthreads();
  const int j = tid & 31, part = tid >> 5;
  float acc = 0.f;
  for (int kk = part * 256; kk < part * 256 + 256; kk++) acc += hrow[kk] * Wf[(size_t)kk * 32 + j];
  red[part][j] = acc;
  __syncthreads();
  if (tid < 32) {
    float s = 0.f;
#pragma unroll
    for (int p = 0; p < 8; p++) s += red[p][tid];
    lg[(size_t)bt * 32 + tid] = s;
  }
}

// ---------------- routing: softmax over 4, top-2, weights -> rw[r][b][h][t] (fp32) ----------------
__global__ __launch_bounds__(256) void routing_k(const float* __restrict__ lg, float* __restrict__ rw) {
  int gid = blockIdx.x * 256 + threadIdx.x;
  if (gid >= 16384) return;
  const int h = gid >> 11;
  const int bt = gid & 2047;
  const int b = bt >> 10, tt = bt & 1023;
  f32x4 l = *(const f32x4*)(lg + (size_t)bt * 32 + h * 4);
  float mx = fmaxf(fmaxf(l[0], l[1]), fmaxf(l[2], l[3]));
  float e0 = __expf(l[0] - mx), e1 = __expf(l[1] - mx), e2 = __expf(l[2] - mx), e3 = __expf(l[3] - mx);
  float den = e0 + e1 + e2 + e3;
  float s[4] = {e0 / den, e1 / den, e2 / den, e3 / den};
  int i1 = 0;
#pragma unroll
  for (int i = 1; i < 4; i++) if (s[i] > s[i1]) i1 = i;
  int i2 = (i1 == 0) ? 1 : 0;
#pragma unroll
  for (int i = 0; i < 4; i++) if (i != i1 && s[i] > s[i2]) i2 = i;
  float sw = s[i1] + s[i2];
  float w1 = s[i1] / sw, w2 = s[i2] / sw;
  float tot = 1.0f + w1 + w2;
  float o[6] = {0.5f / tot, 0.5f / tot, 0.f, 0.f, 0.f, 0.f};
  o[2 + i1] = w1 / tot;
  o[2 + i2] = w2 / tot;
#pragma unroll
  for (int r = 0; r < 6; r++) rw[(size_t)((r * 2 + b) * 8 + h) * 1024 + tt] = o[r];
}

// ---------------- build compacted active-key index lists per (rr,bh) (deterministic scan) --------
__global__ __launch_bounds__(256) void idx_k(const float* __restrict__ rw, int* __restrict__ kidx,
                                             float* __restrict__ maskg, int2* __restrict__ kn) {
  __shared__ int wsum[4];
  const int z = blockIdx.x;            // rr*16 + bh
  const int rr = z >> 4, bh = z & 15;
  const int b = bh >> 3, h = bh & 7;
  const float* rwp = rw + (size_t)(((rr + 2) * 2 + b) * 8 + h) * 1024;
  const int tid = threadIdx.x;
  const int lane = tid & 63, wv = tid >> 6;
  int act[4];
  int c = 0;
#pragma unroll
  for (int j = 0; j < 4; j++) { act[j] = (rwp[tid * 4 + j] != 0.f) ? 1 : 0; c += act[j]; }
  int s = c;
  for (int o = 1; o < 64; o <<= 1) { int t = __shfl_up(s, o, 64); if (lane >= o) s += t; }
  if (lane == 63) wsum[wv] = s;
  __syncthreads();
  int base = 0;
  for (int wi = 0; wi < wv; wi++) base += wsum[wi];
  int excl = base + s - c;
  int Na = wsum[0] + wsum[1] + wsum[2] + wsum[3];
  int* kout = kidx + (size_t)z * 1088;
  float* mout = maskg + (size_t)z * 1088;
  int o = excl;
#pragma unroll
  for (int j = 0; j < 4; j++)
    if (act[j]) { kout[o] = tid * 4 + j; mout[o] = 1.f; o++; }
  for (int i = Na + tid; i < 1088; i += 256) { kout[i] = 0; mout[i] = 0.f; }
  if (tid == 0) kn[z] = make_int2(Na, (Na + 63) & ~63);
}

// ---------------- merged: transpose V (dense) + gather+transpose V (routed) ----------------
__global__ __launch_bounds__(256) void tvvg_k(const bf16_t* __restrict__ qkg, const int* __restrict__ kidx,
                                              const int2* __restrict__ kn, bf16_t* __restrict__ Vt,
                                              bf16_t* __restrict__ Vg) {
  __shared__ __align__(16) bf16_t t[64 * 72];
  __shared__ int idx[64];
  const int blk = blockIdx.x;
  const int tid = threadIdx.x;
  if (blk < 2048) {
    const int x = blk & 15, y = (blk >> 4) & 7, bh = blk >> 7;
    const int tt0 = x * 64, dv0 = y * 64;
    const int b = bh >> 3, h = bh & 7;
    const bf16_t* src = qkg + (size_t)(b * 1024 + tt0) * 12288 + 8192 + h * 512 + dv0;
#pragma unroll
    for (int it = 0; it < 2; it++) {
      int c = tid + it * 256;
      int row = c >> 3, ch = c & 7;
      bf16x8 x8 = *(const bf16x8*)(src + (size_t)row * 12288 + ch * 8);
#pragma unroll
      for (int j = 0; j < 8; j++) t[(ch * 8 + j) * 72 + row] = x8[j];
    }
    __syncthreads();
    bf16_t* dst = Vt + (size_t)bh * 524288 + (size_t)dv0 * 1024 + tt0;
#pragma unroll
    for (int it = 0; it < 2; it++) {
      int c = tid + it * 256;
      int od = c >> 3, ch = c & 7;
      bf16x8 x8 = *(const bf16x8*)(t + od * 72 + ch * 8);
      *(bf16x8*)(dst + (size_t)od * 1024 + ch * 8) = x8;
    }
  } else {
    const int t2 = blk - 2048;
    const int x = t2 & 15, y = (t2 >> 4) & 7, z = t2 >> 7;
    const int rr = z >> 4, bh = z & 15;
    const int b = bh >> 3, h = bh & 7;
    int2 k = kn[z];
    const int s0 = x * 64;
    if (s0 >= k.y) return;
    const int dv0 = y * 64;
    if (tid < 64) idx[tid] = kidx[(size_t)z * 1088 + s0 + tid];
    __syncthreads();
    int base = 0;
    for (int r2 = 0; r2 < rr; r2++) base += kn[r2 * 16 + bh].y;
#pragma unroll
    for (int it = 0; it < 2; it++) {
      int cc = tid + it * 256;
      int row = cc >> 3, ch = cc & 7;
      const bf16_t* src = qkg + (size_t)(b * 1024 + idx[row]) * 12288 + 8192 + h * 512 + dv0 + ch * 8;
      bf16x8 x8 = *(const bf16x8*)src;
#pragma unroll
      for (int j = 0; j < 8; j++) t[(ch * 8 + j) * 72 + row] = x8[j];
    }
    __syncthreads();
    bf16_t* dst = Vg + (size_t)(bh * 512 + dv0) * 2304 + base + s0;
#pragma unroll
    for (int it = 0; it < 2; it++) {
      int cc = tid + it * 256;
      int od = cc >> 3, ch = cc & 7;
      bf16x8 x8 = *(const bf16x8*)(t + od * 72 + ch * 8);
      *(bf16x8*)(dst + (size_t)od * 2304 + ch * 8) = x8;
    }
  }
}

// ---------------- bf16 GEMM, 128x128 tile, BK=64 (A row-major, B stored transposed [N][K]) ----------
template <int MODE>
__global__ __launch_bounds__(256) void gemm_bt(const bf16_t* __restrict__ A, const bf16_t* __restrict__ B,
                                               void* __restrict__ Cp, int K, int lda, int ldb, int ldc) {
  __shared__ __align__(16) bf16_t lsA[128 * 64];
  __shared__ __align__(16) bf16_t lsB[128 * 64];
  const int tid = threadIdx.x;
  const int lane = tid & 63, wv = tid >> 6;
  const int lrow = lane & 15, lgrp = lane >> 4;
  const int wr = wv >> 1, wc = wv & 1;
  const int bn = blockIdx.x * 128, bm = blockIdx.y * 128;

  f32x4 zero = {0.f, 0.f, 0.f, 0.f};
  f32x4 acc[4][4];
#pragma unroll
  for (int i = 0; i < 4; i++)
#pragma unroll
    for (int j = 0; j < 4; j++) acc[i][j] = zero;

  for (int k0 = 0; k0 < K; k0 += 64) {
    __syncthreads();
#pragma unroll
    for (int it = 0; it < 4; it++) {
      int c = tid + it * 256;
      int row = c >> 3, coff = (c & 7) * 16;
      gload16((const char*)A + ((size_t)(bm + row) * lda + k0) * 2 + coff, (char*)lsA + row * 128 + coff);
      gload16((const char*)B + ((size_t)(bn + row) * ldb + k0) * 2 + coff, (char*)lsB + row * 128 + coff);
    }
    __syncthreads();
#pragma unroll
    for (int kk = 0; kk < 2; kk++) {
      bf16x8 af[4], bfr[4];
#pragma unroll
      for (int m4 = 0; m4 < 4; m4++)
        af[m4] = *(const bf16x8*)((const char*)lsA + (wr * 64 + m4 * 16 + lrow) * 128 + kk * 64 + lgrp * 16);
#pragma unroll
      for (int n4 = 0; n4 < 4; n4++)
        bfr[n4] = *(const bf16x8*)((const char*)lsB + (wc * 64 + n4 * 16 + lrow) * 128 + kk * 64 + lgrp * 16);
#pragma unroll
      for (int m4 = 0; m4 < 4; m4++)
#pragma unroll
        for (int n4 = 0; n4 < 4; n4++) acc[m4][n4] = mfma16(af[m4], bfr[n4], acc[m4][n4]);
    }
  }
#pragma unroll
  for (int m4 = 0; m4 < 4; m4++) {
#pragma unroll
    for (int i = 0; i < 4; i++) {
      const int row = bm + wr * 64 + m4 * 16 + lgrp * 4 + i;
#pragma unroll
      for (int n4 = 0; n4 < 4; n4++) {
        const int col = bn + wc * 64 + n4 * 16 + lrow;
        float v = acc[m4][n4][i];
        if constexpr (MODE == 0) {
          ((bf16_t*)Cp)[(size_t)row * ldc + col] = (bf16_t)v;
        } else {
          ((float*)Cp)[(size_t)row * ldc + col] = v;
        }
      }
    }
  }
}

// ---------------- 128x64-tile GEMM (f32 out) for the output projection: 512 blocks ----------------
__global__ __launch_bounds__(256) void gemm_n64(const bf16_t* __restrict__ A, const bf16_t* __restrict__ B,
                                                float* __restrict__ C, int K, int lda, int ldb, int ldc) {
  __shared__ __align__(16) bf16_t lsA[128 * 64];
  __shared__ __align__(16) bf16_t lsB[64 * 64];
  const int tid = threadIdx.x;
  const int lane = tid & 63, wr = tid >> 6;
  const int lrow = lane & 15, lgrp = lane >> 4;
  const int bn = blockIdx.x * 64, bm = blockIdx.y * 128;

  f32x4 zero = {0.f, 0.f, 0.f, 0.f};
  f32x4 acc[2][4];
#pragma unroll
  for (int i = 0; i < 2; i++)
#pragma unroll
    for (int j = 0; j < 4; j++) acc[i][j] = zero;

  for (int k0 = 0; k0 < K; k0 += 64) {
    __syncthreads();
#pragma unroll
    for (int it = 0; it < 4; it++) {
      int c = tid + it * 256;
      int row = c >> 3, coff = (c & 7) * 16;
      gload16((const char*)A + ((size_t)(bm + row) * lda + k0) * 2 + coff, (char*)lsA + row * 128 + coff);
    }
#pragma unroll
    for (int it = 0; it < 2; it++) {
      int c = tid + it * 256;
      int row = c >> 3, coff = (c & 7) * 16;
      gload16((const char*)B + ((size_t)(bn + row) * ldb + k0) * 2 + coff, (char*)lsB + row * 128 + coff);
    }
    __syncthreads();
#pragma unroll
    for (int kk = 0; kk < 2; kk++) {
      bf16x8 af[2], bfr[4];
#pragma unroll
      for (int m2 = 0; m2 < 2; m2++)
        af[m2] = *(const bf16x8*)((const char*)lsA + (wr * 32 + m2 * 16 + lrow) * 128 + kk * 64 + lgrp * 16);
#pragma unroll
      for (int n4 = 0; n4 < 4; n4++)
        bfr[n4] = *(const bf16x8*)((const char*)lsB + (n4 * 16 + lrow) * 128 + kk * 64 + lgrp * 16);
#pragma unroll
      for (int m2 = 0; m2 < 2; m2++)
#pragma unroll
        for (int n4 = 0; n4 < 4; n4++) acc[m2][n4] = mfma16(af[m2], bfr[n4], acc[m2][n4]);
    }
  }
#pragma unroll
  for (int m2 = 0; m2 < 2; m2++) {
#pragma unroll
    for (int i = 0; i < 4; i++) {
      const int row = bm + wr * 32 + m2 * 16 + lgrp * 4 + i;
#pragma unroll
      for (int n4 = 0; n4 < 4; n4++) {
        C[(size_t)row * ldc + bn + n4 * 16 + lrow] = acc[m2][n4][i];
      }
    }
  }
}

// ---------------- merged expert-expansion GEMM: z in [0,16): sel=z>>3 (0=q,1=k), head=z&7 -----------
__global__ __launch_bounds__(256) void gemm_exp(const bf16_t* __restrict__ qkg, const bf16_t* __restrict__ Wqe,
                                                const bf16_t* __restrict__ Wke, bf16_t* __restrict__ qeB,
                                                bf16_t* __restrict__ keB) {
  const int z = blockIdx.z;
  const int sel = z >> 3, hh = z & 7;
  if (sel == 1 && blockIdx.x >= 4) return;
  __shared__ __align__(16) bf16_t lsA[128 * 64];
  __shared__ __align__(16) bf16_t lsB[128 * 64];
  const int tid = threadIdx.x;
  const int lane = tid & 63, wv = tid >> 6;
  const int lrow = lane & 15, lgrp = lane >> 4;
  const int wr = wv >> 1, wc = wv & 1;
  const int bn = blockIdx.x * 128, bm = blockIdx.y * 128;
  const bf16_t* A = qkg + sel * 2048 + hh * 256;
  const bf16_t* B = (sel ? Wke : Wqe) + (size_t)hh * 393216;
  bf16_t* C = sel ? keB : qeB;

  f32x4 zero = {0.f, 0.f, 0.f, 0.f};
  f32x4 acc[4][4];
#pragma unroll
  for (int i = 0; i < 4; i++)
#pragma unroll
    for (int j = 0; j < 4; j++) acc[i][j] = zero;

  for (int k0 = 0; k0 < 256; k0 += 64) {
    __syncthreads();
#pragma unroll
    for (int it = 0; it < 4; it++) {
      int c = tid + it * 256;
      int row = c >> 3, coff = (c & 7) * 16;
      gload16((const char*)A + ((size_t)(bm + row) * 12288 + k0) * 2 + coff, (char*)lsA + row * 128 + coff);
      gload16((const char*)B + ((size_t)(bn + row) * 256 + k0) * 2 + coff, (char*)lsB + row * 128 + coff);
    }
    __syncthreads();
#pragma unroll
    for (int kk = 0; kk < 2; kk++) {
      bf16x8 af[4], bfr[4];
#pragma unroll
      for (int m4 = 0; m4 < 4; m4++)
        af[m4] = *(const bf16x8*)((const char*)lsA + (wr * 64 + m4 * 16 + lrow) * 128 + kk * 64 + lgrp * 16);
#pragma unroll
      for (int n4 = 0; n4 < 4; n4++)
        bfr[n4] = *(const bf16x8*)((const char*)lsB + (wc * 64 + n4 * 16 + lrow) * 128 + kk * 64 + lgrp * 16);
#pragma unroll
      for (int m4 = 0; m4 < 4; m4++)
#pragma unroll
        for (int n4 = 0; n4 < 4; n4++) acc[m4][n4] = mfma16(af[m4], bfr[n4], acc[m4][n4]);
    }
  }
#pragma unroll
  for (int m4 = 0; m4 < 4; m4++) {
#pragma unroll
    for (int i = 0; i < 4; i++) {
      const int row = bm + wr * 64 + m4 * 16 + lgrp * 4 + i;
      const int bb = row >> 10, tt = row & 1023;
#pragma unroll
      for (int n4 = 0; n4 < 4; n4++) {
        const int col = bn + wc * 64 + n4 * 16 + lrow;
        const int rr = col >> 8, dd = col & 255;
        C[((size_t)((rr * 2 + bb) * 8 + hh) * 1024 + tt) * 256 + dd] = (bf16_t)acc[m4][n4][i];
      }
    }
  }
}

// ---------------- gathered K expert expansion: keG[z][slot][256], z = rr*16+bh ----------------
__global__ __launch_bounds__(256) void gemm_kg(const bf16_t* __restrict__ qkg, const bf16_t* __restrict__ Wke,
                                               const int* __restrict__ kidx, const int2* __restrict__ kn,
                                               bf16_t* __restrict__ keG) {
  const int z = blockIdx.z;
  const int rr = z >> 4, bh = z & 15;
  const int bm = blockIdx.y * 128;
  if (bm >= kn[z].y) return;
  __shared__ __align__(16) bf16_t lsA[128 * 64];
  __shared__ __align__(16) bf16_t lsB[128 * 64];
  __shared__ int sidx[128];
  const int b = bh >> 3, h = bh & 7;
  const int bn = blockIdx.x * 128;
  const int tid = threadIdx.x;
  const int lane = tid & 63, wv = tid >> 6;
  const int lrow = lane & 15, lgrp = lane >> 4;
  const int wr = wv >> 1, wc = wv & 1;
  if (tid < 128) sidx[tid] = kidx[(size_t)z * 1088 + bm + tid];
  const bf16_t* Abase = qkg + 2048 + h * 256;
  const bf16_t* B = Wke + (size_t)h * 393216 + (size_t)((rr + 2) * 256 + bn) * 256;

  f32x4 zero = {0.f, 0.f, 0.f, 0.f};
  f32x4 acc[4][4];
#pragma unroll
  for (int i = 0; i < 4; i++)
#pragma unroll
    for (int j = 0; j < 4; j++) acc[i][j] = zero;

  for (int k0 = 0; k0 < 256; k0 += 64) {
    __syncthreads();
#pragma unroll
    for (int it = 0; it < 4; it++) {
      int c = tid + it * 256;
      int row = c >> 3, coff = (c & 7) * 16;
      gload16((const char*)(Abase + ((size_t)(b * 1024 + sidx[row]) * 12288 + k0)) + coff,
              (char*)lsA + row * 128 + coff);
      gload16((const char*)B + ((size_t)row * 256 + k0) * 2 + coff, (char*)lsB + row * 128 + coff);
    }
    __syncthreads();
#pragma unroll
    for (int kk = 0; kk < 2; kk++) {
      bf16x8 af[4], bfr[4];
#pragma unroll
      for (int m4 = 0; m4 < 4; m4++)
        af[m4] = *(const bf16x8*)((const char*)lsA + (wr * 64 + m4 * 16 + lrow) * 128 + kk * 64 + lgrp * 16);
#pragma unroll
      for (int n4 = 0; n4 < 4; n4++)
        bfr[n4] = *(const bf16x8*)((const char*)lsB + (wc * 64 + n4 * 16 + lrow) * 128 + kk * 64 + lgrp * 16);
#pragma unroll
      for (int m4 = 0; m4 < 4; m4++)
#pragma unroll
        for (int n4 = 0; n4 < 4; n4++) acc[m4][n4] = mfma16(af[m4], bfr[n4], acc[m4][n4]);
    }
  }
#pragma unroll
  for (int m4 = 0; m4 < 4; m4++) {
#pragma unroll
    for (int i = 0; i < 4; i++) {
      const int row = bm + wr * 64 + m4 * 16 + lgrp * 4 + i;
#pragma unroll
      for (int n4 = 0; n4 < 4; n4++) {
        const int col = bn + wc * 64 + n4 * 16 + lrow;
        keG[((size_t)z * 1088 + row) * 256 + col] = (bf16_t)acc[m4][n4][i];
      }
    }
  }
}

// ---------------- fused masked attention (round-13 proven config) ----------------
// 512 blocks XCD-swizzled, 256 threads (4 waves x 16 q-rows), 2 blocks/CU.
// K+V staged via global_load_lds double-buffer, one barrier/tile; routed K linear from keG.
__global__ __launch_bounds__(256, 2) void attn_k(const bf16_t* __restrict__ qe, const bf16_t* __restrict__ ke,
                                                 const bf16_t* __restrict__ keG, const bf16_t* __restrict__ Vt,
                                                 const float* __restrict__ rw, const bf16_t* __restrict__ g,
                                                 bf16_t* __restrict__ oc, const float* __restrict__ maskg,
                                                 const int2* __restrict__ kn, const bf16_t* __restrict__ Vg) {
  __shared__ __align__(16) bf16_t ldsK[2][32 * 256];   // [buf][row 512B], swz: off ^= (row&7)<<4
  __shared__ __align__(16) bf16_t ldsV[2][256 * 32];   // [buf][row 64B],  swz: off ^= ((row>>1)&3)<<4
  __shared__ __align__(16) bf16_t ldsP[4 * 16 * 40];   // per-wave 16 q x 32 keys, row-permuted

  const int f = (blockIdx.x & 7) * 64 + (blockIdx.x >> 3);
  const int qt = f & 15, dvh = (f >> 4) & 1, bh = f >> 5;

  const int tid = threadIdx.x;
  const int wv = tid >> 6, lane = tid & 63;
  const int lrow = lane & 15, lgrp = lane >> 4;
  const int b = bh >> 3, h = bh & 7;
  const int qw = qt * 64 + wv * 16;

  const char* vtb = (const char*)Vt + ((size_t)bh * 524288 + (size_t)dvh * 262144) * 2;

  f32x4 zero = {0.f, 0.f, 0.f, 0.f};
  f32x4 Otot[16];
#pragma unroll
  for (int n = 0; n < 16; n++) Otot[n] = zero;

  int cur = 0;
  for (int r = 0; r < 6; r++) {
    const size_t rbh = (size_t)((r * 2 + b) * 8 + h);
    const bf16_t* qbase = qe + rbh * 262144;
    const float* rwb = rw + rbh * 1024;

    int nkt = 32;
    float lpinit = 0.f;
    const float* mgp = nullptr;
    const char* vgb = vtb;
    size_t vstride = 2048;
    const char* kbase = (const char*)ke + rbh * 524288;
    const bool routed = (r >= 2);
    if (routed) {
      const int rr = r - 2;
      int2 kkn = kn[rr * 16 + bh];
      nkt = kkn.y >> 5;
      lpinit = (float)(1024 - kkn.x) * 0.0625f;
      int basep = 0;
      for (int r2 = 0; r2 < rr; r2++) basep += kn[r2 * 16 + bh].y;
      vgb = (const char*)Vg + ((size_t)(bh * 512 + dvh * 256) * 2304 + basep) * 2;
      vstride = 4608;
      mgp = maskg + (size_t)(rr * 16 + bh) * 1088;
      kbase = (const char*)keG + (size_t)(rr * 16 + bh) * 557056;   // 1088*512 bytes
    }
    if (nkt == 0) continue;

    bf16x8 qf[8];
#pragma unroll
    for (int c = 0; c < 8; c++)
      qf[c] = *(const bf16x8*)(qbase + (size_t)(qw + lrow) * 256 + c * 32 + lgrp * 8);
    float rwq[4];
#pragma unroll
    for (int i = 0; i < 4; i++) rwq[i] = rwb[qw + lgrp * 4 + i];

    float Lp[4] = {lpinit, lpinit, lpinit, lpinit};
    f32x4 accO[16];
#pragma unroll
    for (int n = 0; n < 16; n++) accO[n] = zero;

    auto issue_tile = [&](int kt, int buf) {
      char* lk = (char*)ldsK[buf];
#pragma unroll
      for (int it = 0; it < 4; it++) {
        int p = (wv * 4 + it) * 1024 + (lane << 4);
        int row = p >> 9, off = p & 511;
        gload16(kbase + (size_t)(kt * 32 + row) * 512 + (off ^ ((row & 7) << 4)), lk + p);
      }
      char* lv = (char*)ldsV[buf];
      const char* vb = vgb + (size_t)kt * 64;
#pragma unroll
      for (int it = 0; it < 4; it++) {
        int p = (wv * 4 + it) * 1024 + (lane << 4);
        int row = p >> 6, off = p & 63;
        gload16(vb + (size_t)row * vstride + (off ^ (((row >> 1) & 3) << 4)), lv + p);
      }
    };

    issue_tile(0, cur);
    for (int kt = 0; kt < nkt; kt++) {
      asm volatile("s_waitcnt vmcnt(0) lgkmcnt(0)" ::: "memory");
      __syncthreads();
      if (kt + 1 < nkt) issue_tile(kt + 1, cur ^ 1);
      const char* lK = (const char*)ldsK[cur];
      const char* lV = (const char*)ldsV[cur];
      float mg0 = 1.f, mg1 = 1.f;
      if (routed) { mg0 = mgp[kt * 32 + lrow]; mg1 = mgp[kt * 32 + 16 + lrow]; }

      // S = Q K^T (two 16-key column blocks), swizzled reads
      f32x4 sac0 = zero, sac1 = zero;
      __builtin_amdgcn_s_setprio(1);
#pragma unroll
      for (int c = 0; c < 8; c++) {
        int col = (c * 64 + lgrp * 16) ^ ((lrow & 7) << 4);
        bf16x8 k0 = *(const bf16x8*)(lK + (size_t)lrow * 512 + col);
        bf16x8 k1 = *(const bf16x8*)(lK + (size_t)(16 + lrow) * 512 + col);
        sac0 = mfma16(qf[c], k0, sac0);
        sac1 = mfma16(qf[c], k1, sac1);
      }
      __builtin_amdgcn_s_setprio(0);
      // fixed-M softmax; gathered pad slots have mg=0 -> P=0, denom+=0
      bf16_t* pb = ldsP + wv * 640;
#pragma unroll
      for (int i = 0; i < 4; i++) {
        float p0 = mg0 * __expf(sac0[i] * 0.0625f);
        float p1 = mg1 * __expf(sac1[i] * 0.0625f);
        pb[(i * 4 + lgrp) * 40 + lrow] = (bf16_t)p0;
        pb[(i * 4 + lgrp) * 40 + 16 + lrow] = (bf16_t)p1;
        Lp[i] += p0 + p1;
      }
      bf16x8 pa = *(const bf16x8*)(pb + ((lrow & 3) * 4 + (lrow >> 2)) * 40 + lgrp * 8);
      __builtin_amdgcn_s_setprio(1);
#pragma unroll
      for (int n = 0; n < 16; n++) {
        int row = n * 16 + lrow;
        int col = (lgrp * 16) ^ (((row >> 1) & 3) << 4);
        bf16x8 vf = *(const bf16x8*)(lV + (size_t)row * 64 + col);
        accO[n] = mfma16(pa, vf, accO[n]);
      }
      __builtin_amdgcn_s_setprio(0);
      cur ^= 1;
    }  // kt
#pragma unroll
    for (int i = 0; i < 4; i++) {
      float v = Lp[i];
      v += __shfl_xor(v, 1, 16);
      v += __shfl_xor(v, 2, 16);
      v += __shfl_xor(v, 4, 16);
      v += __shfl_xor(v, 8, 16);
      float inv = rwq[i] / v;
#pragma unroll
      for (int n = 0; n < 16; n++) Otot[n][i] += accO[n][i] * inv;
    }
  }  // r

  // epilogue: o * silu(g) -> O_comb bf16 (g = qkg cols [4096,8192), row stride 12288)
#pragma unroll
  for (int i = 0; i < 4; i++) {
    const size_t grow = ((size_t)(b * 1024 + qw + lgrp * 4 + i)) * 12288 + 4096 + h * 512 + dvh * 256;
    const size_t orow = ((size_t)(b * 1024 + qw + lgrp * 4 + i)) * 4096 + h * 512 + dvh * 256;
#pragma unroll
    for (int n = 0; n < 16; n++) {
      float gv = (float)g[grow + n * 16 + lrow];
      float sg = gv / (1.f + __expf(-gv));
      oc[orow + n * 16 + lrow] = (bf16_t)(Otot[n][i] * sg);
    }
  }
}

// =====================================================================================
extern "C" void kernel_launch(void* const* d_in, const int* in_sizes, int n_in,
                              void* d_out, int out_size, void* d_ws, size_t ws_size,
                              hipStream_t stream) {
  const float* hs  = (const float*)d_in[0];
  const float* Wq  = (const float*)d_in[1];
  const float* Wk  = (const float*)d_in[2];
  const float* Wv  = (const float*)d_in[3];
  const float* Wqe = (const float*)d_in[4];
  const float* Wke = (const float*)d_in[5];
  const float* Wgt = (const float*)d_in[6];
  const float* Wg  = (const float*)d_in[7];
  const float* Wo  = (const float*)d_in[8];
  float* out = (float*)d_out;

  // Liveness-aware workspace layout; peak footprint ~252 MiB.
  const size_t MB = 1024 * 1024;
  char* w = (char*)d_ws;
  bf16_t* hs_bf = (bf16_t*)(w + 0 * MB);    // 8MB, dead after mega-proj
  bf16_t* WcatT = (bf16_t*)(w + 8 * MB);    // 48MB, dead after proj
  bf16_t* qeB   = (bf16_t*)(w + 0 * MB);    // 48MB, written AFTER proj (overlays)
  bf16_t* WoT   = (bf16_t*)(w + 56 * MB);   // 16MB
  bf16_t* WqeT  = (bf16_t*)(w + 72 * MB);   // 6MB
  bf16_t* WkeT  = (bf16_t*)(w + 78 * MB);   // 6MB
  bf16_t* qkg   = (bf16_t*)(w + 84 * MB);   // 48MB: [2048][12288] = q|k|g|v
  bf16_t* Vt    = (bf16_t*)(w + 132 * MB);  // 16MB
  bf16_t* keB   = (bf16_t*)(w + 148 * MB);  // 16MB (shared experts only)
  bf16_t* keG   = (bf16_t*)(w + 164 * MB);  // 34MB: [64][1088][256]
  bf16_t* ocB   = (bf16_t*)(w + 198 * MB);  // 16MB
  bf16_t* VgB   = (bf16_t*)(w + 214 * MB);  // 36MB: [16][512][2304]
  float*  Wf    = (float*)(w + 250 * MB);               // 256KB
  float*  lg    = (float*)(w + 250 * MB + 262144);      // 256KB
  float*  rwB   = (float*)(w + 250 * MB + 524288);      // 384KB
  int*    kidxB = (int*)(w + 251 * MB);                 // 272KB
  float*  maskgB= (float*)(w + 251 * MB + 524288);      // 272KB
  int2*   knB   = (int2*)(w + 251 * MB + 1048576);      // 512B
  (void)ws_size; (void)in_sizes; (void)n_in; (void)out_size;

  // merged conversions/transposes (1 dispatch)
  prep_k<<<11776, 256, 0, stream>>>(hs, hs_bf, Wq, Wk, Wg, Wv, Wo, Wqe, Wke, WcatT, WoT, WqeT, WkeT);

  // fp32 routing path + compaction
  wfuse_k<<<32, 256, 0, stream>>>(Wq, Wgt, Wf);
  logits_k<<<2048, 256, 0, stream>>>(hs, Wf, lg);
  routing_k<<<64, 256, 0, stream>>>(lg, rwB);
  idx_k<<<64, 256, 0, stream>>>(rwB, kidxB, maskgB, knB);

  // single mega projection q|k|g|v (N=12288)
  gemm_bt<0><<<dim3(96, 16, 1), 256, 0, stream>>>(hs_bf, WcatT, qkg, 2048, 2048, 2048, 12288);

  // merged V transpose (dense) + V gather (routed), 1 dispatch
  tvvg_k<<<10240, 256, 0, stream>>>(qkg, kidxB, knB, Vt, VgB);

  // expert expansions: qe dense (all), ke dense (shared only), keG gathered (routed)
  gemm_exp<<<dim3(12, 16, 16), 256, 0, stream>>>(qkg, WqeT, WkeT, qeB, keB);
  gemm_kg<<<dim3(2, 8, 64), 256, 0, stream>>>(qkg, WkeT, kidxB, knB, keG);

  // fused attention: dense shared experts + gathered routed experts (linear K loads)
  attn_k<<<512, 256, 0, stream>>>(qeB, keB, keG, Vt, rwB, qkg, ocB, maskgB, knB, VgB);

  // output projection (fp32 out, 128x64 tiles -> 512 blocks)
  gemm_n64<<<dim3(32, 16, 1), 256, 0, stream>>>(ocB, WoT, out, 4096, 4096, 4096, 2048);
}